// Round 1
// baseline (8156.329 us; speedup 1.0000x reference)
//
#include <hip/hip_runtime.h>
#include <math.h>

typedef unsigned short u16;
typedef unsigned int   u32;
typedef unsigned long long u64;
typedef _Float16 f16;
typedef __attribute__((ext_vector_type(8))) _Float16 f16x8;
typedef __attribute__((ext_vector_type(4))) float    f32x4;
typedef __attribute__((ext_vector_type(4))) u32      u32x4;

#define T_SEQ 1024
#define NB    64
#define HID   512
#define KC    384       // 3*128 combined conv+Wx K
#define G4    2048      // 4*HID
#define MR    (NB*T_SEQ) // 65536
#define ZD2   128       // 2*ZD

// ---------------- static device buffers ----------------
__device__ __align__(16) f16   g_xwin[(size_t)MR*KC];    // 48 MB window-matrix (f16)
__device__ __align__(16) f16   g_cwxt[(size_t)G4*KC];    // combined (conv_w@Wx)^T  [n][k]
__device__              float  g_bb[G4];                 // conv_b@Wx + b
__device__ __align__(16) f16   g_whT[(size_t)G4*HID];    // Wh^T [2048][512]
__device__ __align__(16) f16   g_w1T[(size_t)HID*HID];
__device__ __align__(16) f16   g_w2T[(size_t)ZD2*HID];
__device__              float  g_b1f[HID];
__device__              float  g_b2f[ZD2];
__device__ __align__(16) float g_XW[(size_t)MR*G4];      // 512 MB x-side pre-activations
__device__ __align__(16) f16   g_hseq[(size_t)MR*HID];   // 64 MB
__device__ __align__(16) f16   g_tmp1[(size_t)MR*HID];   // 64 MB
// h broadcast ring: one fresh 64x512 slot per timestep, packed 4 cols / u64.
// Slots 1..T are pre-filled with the sentinel 0xFFFF... (f16 -NaN, unreachable
// for h = o*tanh(c)); the DATA is the synchronization flag.
__device__ __align__(16) u64   g_hstep[(size_t)(T_SEQ+1)*NB*128];
__device__              int    g_in_fp32;

// ---------------- helpers ----------------
__device__ inline float bf2f(u16 u){ union{u32 i; float f;} v; v.i = ((u32)u)<<16; return v.f; }
__device__ inline u16  f2bf(float f){ union{u32 i; float f;} v; v.f = f; u32 u = v.i;
                                      return (u16)((u + 0x7fffu + ((u>>16)&1u))>>16); }
__device__ inline float load_in(const void* p, size_t i){
  return g_in_fp32 ? ((const float*)p)[i] : bf2f(((const u16*)p)[i]);
}
__device__ inline float fsig(float x){
  return __builtin_amdgcn_rcpf(1.f + __builtin_amdgcn_exp2f(-1.44269504f*x));
}
__device__ inline float ftanh(float x){
  x = fminf(fmaxf(x, -10.f), 10.f);
  float e = __builtin_amdgcn_exp2f(2.88539008f*x);
  return (e - 1.f) * __builtin_amdgcn_rcpf(e + 1.f);
}

// ---------------- dtype probe ----------------
__global__ void k_probe(const void* x){
  __shared__ int cnt;
  if (threadIdx.x == 0) cnt = 0;
  __syncthreads();
  int loc = 0;
  for (int i = threadIdx.x; i < 4096; i += 256){
    float a = fabsf(bf2f(((const u16*)x)[i]));
    if (a > 0.01f && a < 10.f) loc++;
  }
  atomicAdd(&cnt, loc);
  __syncthreads();
  if (threadIdx.x == 0) g_in_fp32 = (cnt < 3276) ? 1 : 0;
}

// ---------------- init: h slot0 = 0, fp32 biases ----------------
__global__ void k_init(const void* b1, const void* b2){
  int i = blockIdx.x*256 + threadIdx.x;
  if (i < HID)        g_b1f[i] = load_in(b1, i);
  if (i < ZD2)        g_b2f[i] = load_in(b2, i);
  if (i < NB*128)     g_hstep[i] = 0ULL;      // slot 0 = h_0 = zeros
}

// ---------------- sentinel-fill ring slots 1..T ----------------
__global__ void k_fill(){
  size_t i = (size_t)blockIdx.x*256 + threadIdx.x;
  u64* p = g_hstep + (size_t)NB*128;
  const size_t n = (size_t)T_SEQ*NB*128;
  for (size_t j = i; j < n; j += (size_t)4096*256) p[j] = ~0ULL;
}

// ---------------- combine conv_w@Wx -> CWx^T, and bb = conv_b@Wx + b ----------------
__global__ void k_combine(const void* conv_w, const void* conv_b, const void* Wx, const void* b){
  int j  = blockIdx.x*256 + threadIdx.x;  // 0..2047
  int kc = blockIdx.y;                    // 0..384 (384 = bias row)
  float acc = 0.f;
  if (kc < KC){
    for (int m = 0; m < HID; ++m)
      acc += load_in(conv_w, (size_t)kc*HID + m) * load_in(Wx, (size_t)m*G4 + j);
    g_cwxt[(size_t)j*KC + kc] = (f16)acc;
  } else {
    for (int m = 0; m < HID; ++m)
      acc += load_in(conv_b, m) * load_in(Wx, (size_t)m*G4 + j);
    g_bb[j] = acc + load_in(b, j);
  }
}

// ---------------- transposes (src [R][C] -> dst [C][R]) ----------------
__device__ inline void trans_body(const void* src, f16* dst, int R, int C){
  size_t i = (size_t)blockIdx.x*256 + threadIdx.x;
  if (i >= (size_t)R*C) return;
  int c = (int)(i / (size_t)R), r = (int)(i % (size_t)R);
  dst[i] = (f16)load_in(src, (size_t)r*C + c);
}
__global__ void k_trans_wh(const void* Wh){ trans_body(Wh, g_whT, HID, G4); }
__global__ void k_trans_w1(const void* W1){ trans_body(W1, g_w1T, HID, HID); }
__global__ void k_trans_w2(const void* W2){ trans_body(W2, g_w2T, HID, ZD2); }

// ---------------- build sliding-window matrix (SAME pad) ----------------
__global__ void k_xwin(const void* x){
  size_t i = (size_t)blockIdx.x*256 + threadIdx.x;
  if (i >= (size_t)MR*KC) return;
  int row = (int)(i / KC), kc = (int)(i % KC);
  int k = kc >> 7, c = kc & 127;
  int b = row >> 10, t = row & 1023;
  int ts = t - 1 + k;
  float v = 0.f;
  if (ts >= 0 && ts < T_SEQ) v = load_in(x, ((size_t)b*T_SEQ + ts)*128 + c);
  g_xwin[i] = (f16)v;
}

// ---------------- generic MFMA f16 GEMM: C = act(A[M,K] @ BT[N,K]^T + bias) ----------------
template<int MODE, int K>
__device__ inline void gemm_body(const f16* __restrict__ A, const f16* __restrict__ BT,
                                 const float* __restrict__ bias, void* __restrict__ C, int N){
  const int tid = threadIdx.x;
  const int w = tid >> 6, lane = tid & 63;
  const int q = lane >> 4, ln = lane & 15;
  const int n0 = blockIdx.x * 128;
  const int m0 = blockIdx.y * 64;
  const f16* ap = A + (size_t)(m0 + w*16 + ln)*K + q*8;
  const f16* bp = BT + (size_t)(n0 + ln)*K + q*8;
  f32x4 acc[8] = {};
  #pragma unroll 4
  for (int k = 0; k < K; k += 32){
    f16x8 af = *(const f16x8*)(ap + k);
    #pragma unroll
    for (int nt = 0; nt < 8; ++nt){
      f16x8 bf = *(const f16x8*)(bp + (size_t)nt*16*K + k);
      acc[nt] = __builtin_amdgcn_mfma_f32_16x16x32_f16(af, bf, acc[nt], 0, 0, 0);
    }
  }
  const int f32o = g_in_fp32;
  #pragma unroll
  for (int nt = 0; nt < 8; ++nt){
    const int col = n0 + nt*16 + ln;
    const float bv = bias[col];
    #pragma unroll
    for (int r = 0; r < 4; ++r){
      const int row = m0 + w*16 + q*4 + r;
      float v = acc[nt][r] + bv;
      if (MODE == 0){
        ((float*)C)[(size_t)row*N + col] = v;
      } else if (MODE == 1){
        ((f16*)C)[(size_t)row*N + col] = (f16)fmaxf(v, 0.f);
      } else {
        size_t idx = (col < 64) ? ((size_t)row*64 + col)
                                : (4194304UL + (size_t)row*64 + (size_t)(col - 64));
        if (f32o) ((float*)C)[idx] = v;
        else      ((u16*)C)[idx]   = f2bf(v);
      }
    }
  }
}
__global__ __launch_bounds__(256) void k_gemm_xw(){   gemm_body<0,KC >(g_xwin, g_cwxt, g_bb,  g_XW,   G4 ); }
__global__ __launch_bounds__(256) void k_gemm_mlp1(){ gemm_body<1,HID>(g_hseq, g_w1T,  g_b1f, g_tmp1, HID); }
__global__ __launch_bounds__(256) void k_gemm_mlp2(void* out){ gemm_body<2,HID>(g_tmp1, g_w2T, g_b2f, out, ZD2); }

// ---------------- persistent LSTM ----------------
// Sentinel-dataflow version: no flags, no per-step barriers, no LDS.
// - Wh fragments live in registers for the whole kernel (128 VGPRs; 1 wave/SIMD).
// - Consumers poll the h ring directly with 16B L1/L2-bypassing loads until the
//   sentinel (0xFFFF per f16) is gone; producers store h fire-and-forget.
// - The 4 waves of a WG are fully independent pipelines (each owns 16 batch rows).
__global__ __launch_bounds__(256, 1) void k_lstm(){
  const int g   = blockIdx.x;
  const int tid = threadIdx.x;
  const int w = tid >> 6, lane = tid & 63;
  const int q = lane >> 4, ln = lane & 15;
  const int  c8 = ln & 7;
  const bool lo = ln < 8;
  const int  zc0  = (lo ? 0 : HID)       + g*8 + c8;   // i | f column in XW
  const int  zc1  = (lo ? 2*HID : 3*HID) + g*8 + c8;   // g | o column in XW
  const int  colh = g*8 + c8;
  const int  am   = w*16 + ln;                          // A-frag row (batch)

  // ---- loop-invariant Wh B-fragments into registers (once) ----
  // b0 row = ln     -> zcol = (ln>>3)*HID     + g*8 + c8   (i: ln<8, f: ln>=8)
  // b1 row = 16+ln  -> zcol = (2+(ln>>3))*HID + g*8 + c8   (g: ln<8, o: ln>=8)
  const size_t zA = (size_t)((ln>>3)*HID     + g*8 + c8) * HID;
  const size_t zB = (size_t)((2+(ln>>3))*HID + g*8 + c8) * HID;
  f16x8 bf0[16], bf1[16];
  #pragma unroll
  for (int kk = 0; kk < 16; ++kk){
    bf0[kk] = *(const f16x8*)&g_whT[zA + kk*32 + q*8];
    bf1[kk] = *(const f16x8*)&g_whT[zB + kk*32 + q*8];
  }

  float c_st[4] = {0.f, 0.f, 0.f, 0.f};

  // ---- XW prefetch for t=0 ----
  size_t rowb[4];
  #pragma unroll
  for (int r = 0; r < 4; ++r) rowb[r] = (size_t)(w*16 + q*4 + r)*T_SEQ*G4;
  float xwa[4], xwb[4];
  #pragma unroll
  for (int r = 0; r < 4; ++r){
    xwa[r] = g_XW[rowb[r] + zc0];
    xwb[r] = g_XW[rowb[r] + zc1];
  }

  // per-lane byte address of this lane's h fragment in slot 0
  u64 addr = (u64)(const void*)(g_hstep + ((size_t)am)*128 + (size_t)q*2);

  for (int t = 0; t < T_SEQ; ++t){
    // ---- poll-load h_t: 16 x 16B cache-bypassing loads, retry until no sentinel ----
    u32x4 hr[16];
    for (;;){
      asm volatile(
        "global_load_dwordx4 %0, %16, off sc0 sc1\n"
        "global_load_dwordx4 %1, %16, off offset:64 sc0 sc1\n"
        "global_load_dwordx4 %2, %16, off offset:128 sc0 sc1\n"
        "global_load_dwordx4 %3, %16, off offset:192 sc0 sc1\n"
        "global_load_dwordx4 %4, %16, off offset:256 sc0 sc1\n"
        "global_load_dwordx4 %5, %16, off offset:320 sc0 sc1\n"
        "global_load_dwordx4 %6, %16, off offset:384 sc0 sc1\n"
        "global_load_dwordx4 %7, %16, off offset:448 sc0 sc1\n"
        "global_load_dwordx4 %8, %16, off offset:512 sc0 sc1\n"
        "global_load_dwordx4 %9, %16, off offset:576 sc0 sc1\n"
        "global_load_dwordx4 %10, %16, off offset:640 sc0 sc1\n"
        "global_load_dwordx4 %11, %16, off offset:704 sc0 sc1\n"
        "global_load_dwordx4 %12, %16, off offset:768 sc0 sc1\n"
        "global_load_dwordx4 %13, %16, off offset:832 sc0 sc1\n"
        "global_load_dwordx4 %14, %16, off offset:896 sc0 sc1\n"
        "global_load_dwordx4 %15, %16, off offset:960 sc0 sc1\n"
        "s_waitcnt vmcnt(0)"
        : "=&v"(hr[0]),  "=&v"(hr[1]),  "=&v"(hr[2]),  "=&v"(hr[3]),
          "=&v"(hr[4]),  "=&v"(hr[5]),  "=&v"(hr[6]),  "=&v"(hr[7]),
          "=&v"(hr[8]),  "=&v"(hr[9]),  "=&v"(hr[10]), "=&v"(hr[11]),
          "=&v"(hr[12]), "=&v"(hr[13]), "=&v"(hr[14]), "=&v"(hr[15])
        : "v"(addr)
        : "memory");
      u32 bad = 0;
      #pragma unroll
      for (int i = 0; i < 16; ++i){
        bad |= (u32)((hr[i].x & hr[i].y) == 0xFFFFFFFFu);
        bad |= (u32)((hr[i].z & hr[i].w) == 0xFFFFFFFFu);
      }
      if (!__any((int)bad)) break;
      __builtin_amdgcn_s_sleep(1);
    }
    addr += (u64)NB*128*8;   // next slot

    // ---- prefetch XW for t+1 (latency hides under MFMA+gates+store+next poll) ----
    const int tn = (t+1 < T_SEQ) ? (t+1) : t;
    float xna[4], xnb[4];
    #pragma unroll
    for (int r = 0; r < 4; ++r){
      const size_t base = rowb[r] + (size_t)tn*G4;
      xna[r] = g_XW[base + zc0];
      xnb[r] = g_XW[base + zc1];
    }

    // ---- MFMA: pure-register, 4 accumulator chains ----
    f32x4 a0a = {0.f,0.f,0.f,0.f}, a0b = {0.f,0.f,0.f,0.f};
    f32x4 a1a = {0.f,0.f,0.f,0.f}, a1b = {0.f,0.f,0.f,0.f};
    #pragma unroll
    for (int kk = 0; kk < 16; ++kk){
      f16x8 af = __builtin_bit_cast(f16x8, hr[kk]);
      if (kk & 1){
        a0b = __builtin_amdgcn_mfma_f32_16x16x32_f16(af, bf0[kk], a0b, 0, 0, 0);
        a1b = __builtin_amdgcn_mfma_f32_16x16x32_f16(af, bf1[kk], a1b, 0, 0, 0);
      } else {
        a0a = __builtin_amdgcn_mfma_f32_16x16x32_f16(af, bf0[kk], a0a, 0, 0, 0);
        a1a = __builtin_amdgcn_mfma_f32_16x16x32_f16(af, bf1[kk], a1a, 0, 0, 0);
      }
    }
    f32x4 a0 = a0a + a0b;
    f32x4 a1 = a1a + a1b;

    // ---- gates + fire-and-forget h publish ----
    f16 h16v[4];
    #pragma unroll
    for (int r = 0; r < 4; ++r){
      float z0 = a0[r] + xwa[r];          // i (lo) | f (hi)
      float z1 = a1[r] + xwb[r];          // g (lo) | o (hi)
      float zf = __shfl_xor(z0, 8, 64);
      float zo = __shfl_xor(z1, 8, 64);
      float iv = fsig(z0);
      float fv = fsig(zf);
      float gv = ftanh(z1);
      float ov = fsig(zo);
      float cn = fv*c_st[r] + iv*gv;
      c_st[r] = cn;
      float hvf = ov*ftanh(cn);
      f16 h16 = (f16)hvf;
      h16v[r] = h16;
      u32 me = (u32)__builtin_bit_cast(u16, h16);
      u32 p1 = me | (((u32)__shfl_xor((int)me, 1, 64)) << 16);   // cols c8,c8+1 (even c8)
      u32 p2 = (u32)__shfl_xor((int)p1, 2, 64);                  // cols c8+2,c8+3
      u64 pk = (u64)p1 | ((u64)p2 << 32);
      if (lo && (c8 & 3) == 0){
        int m = w*16 + q*4 + r;
        __hip_atomic_store(g_hstep + ((size_t)(t+1)*NB + m)*128 + (size_t)g*2 + (c8>>2),
                           pk, __ATOMIC_RELAXED, __HIP_MEMORY_SCOPE_AGENT);
      }
    }
    // hseq stores: consumed only by k_gemm_mlp1 (cross-kernel flush at dispatch end)
    if (lo){
      #pragma unroll
      for (int r = 0; r < 4; ++r){
        int m = w*16 + q*4 + r;
        g_hseq[((size_t)m*T_SEQ + t)*HID + colh] = h16v[r];
      }
    }
    // rotate XW double-buffer
    #pragma unroll
    for (int r = 0; r < 4; ++r){ xwa[r] = xna[r]; xwb[r] = xnb[r]; }
  }
}

// ---------------- launch ----------------
extern "C" void kernel_launch(void* const* d_in, const int* in_sizes, int n_in,
                              void* d_out, int out_size, void* d_ws, size_t ws_size,
                              hipStream_t stream){
  const void* x      = d_in[0];
  const void* conv_w = d_in[1];
  const void* conv_b = d_in[2];
  const void* Wx     = d_in[3];
  const void* Wh     = d_in[4];
  const void* b      = d_in[5];
  const void* W1     = d_in[6];
  const void* b1     = d_in[7];
  const void* W2     = d_in[8];
  const void* b2     = d_in[9];
  (void)in_sizes; (void)n_in; (void)out_size; (void)d_ws; (void)ws_size;

  hipLaunchKernelGGL(k_probe,   dim3(1),        dim3(256), 0, stream, x);
  hipLaunchKernelGGL(k_init,    dim3(256),      dim3(256), 0, stream, b1, b2);
  hipLaunchKernelGGL(k_fill,    dim3(4096),     dim3(256), 0, stream);
  hipLaunchKernelGGL(k_combine, dim3(8, 385),   dim3(256), 0, stream, conv_w, conv_b, Wx, b);
  hipLaunchKernelGGL(k_trans_wh,dim3(4096),     dim3(256), 0, stream, Wh);
  hipLaunchKernelGGL(k_trans_w1,dim3(1024),     dim3(256), 0, stream, W1);
  hipLaunchKernelGGL(k_trans_w2,dim3(256),      dim3(256), 0, stream, W2);
  hipLaunchKernelGGL(k_xwin,    dim3(98304),    dim3(256), 0, stream, x);
  hipLaunchKernelGGL(k_gemm_xw, dim3(16, 1024), dim3(256), 0, stream);
  hipLaunchKernelGGL(k_lstm,    dim3(64),       dim3(256), 0, stream);
  hipLaunchKernelGGL(k_gemm_mlp1, dim3(4, 1024), dim3(256), 0, stream);
  hipLaunchKernelGGL(k_gemm_mlp2, dim3(1, 1024), dim3(256), 0, stream, d_out);
}